// Round 1
// baseline (676.154 us; speedup 1.0000x reference)
//
#include <hip/hip_runtime.h>
#include <math.h>

#define HID 64
#define HEADS 8
#define NUM_LAYERS 3

// ---------------------------------------------------------------------------
// degree / normalization
// ---------------------------------------------------------------------------
__global__ void k_init_deg(float* deg, int n) {
    int i = blockIdx.x * blockDim.x + threadIdx.x;
    if (i < n) deg[i] = 1.0f;  // self-loop contributes 1
}

__global__ void k_count_deg(const int* __restrict__ col, float* deg, int E) {
    int e = blockIdx.x * blockDim.x + threadIdx.x;
    if (e < E) atomicAdd(&deg[col[e]], 1.0f);
}

__global__ void k_dinv(float* deg, int n) {
    int i = blockIdx.x * blockDim.x + threadIdx.x;
    if (i < n) deg[i] = rsqrtf(deg[i]);  // deg >= 1 always (self-loop)
}

// ---------------------------------------------------------------------------
// lin1: h = relu(x @ W1 + b1),  x: n x 256, W1: 256 x 64
// block = 256 threads = 4 nodes x 64 out-channels; x rows staged in LDS
// ---------------------------------------------------------------------------
__global__ __launch_bounds__(256) void k_lin1(const float* __restrict__ x,
                                              const float* __restrict__ w,
                                              const float* __restrict__ b,
                                              float* __restrict__ h, int n) {
    __shared__ float xs[4][256];
    int oc  = threadIdx.x & 63;
    int sub = threadIdx.x >> 6;
    int node0 = blockIdx.x * 4;
    for (int i = threadIdx.x; i < 4 * 256; i += 256) {
        int r = i >> 8, c = i & 255;
        int node = node0 + r;
        xs[r][c] = (node < n) ? x[(size_t)node * 256 + c] : 0.f;
    }
    __syncthreads();
    int node = node0 + sub;
    if (node >= n) return;
    float acc = 0.f;
#pragma unroll 8
    for (int c = 0; c < 256; ++c) acc += xs[sub][c] * w[c * 64 + oc];
    acc += b[oc];
    h[(size_t)node * 64 + oc] = fmaxf(acc, 0.f);
}

// ---------------------------------------------------------------------------
// batched 64x64 GEMM for q / K / V of one layer.
// grid.y = job: 0 -> q (from slice `layer`), 1..t -> K slice s, t+1..2t -> V.
// Slices >= 1 hold raw (pre-relu) segment sums; relu applied on read.
// ---------------------------------------------------------------------------
__global__ __launch_bounds__(256) void k_qkv(
    const float* __restrict__ xsbase,
    const float* __restrict__ wq, const float* __restrict__ bq,
    const float* __restrict__ wk, const float* __restrict__ bk,
    const float* __restrict__ wv, const float* __restrict__ bv,
    float* __restrict__ q, float* __restrict__ K, float* __restrict__ V,
    int n, int layer, int t) {
    int job = blockIdx.y;
    const float* src; const float* w; const float* b; float* dst; bool relu_in;
    if (job == 0) {
        src = xsbase + (size_t)layer * n * 64;
        w = wq + layer * 4096; b = bq + layer * 64; dst = q;
        relu_in = (layer >= 1);
    } else if (job <= t) {
        int s = job - 1;
        src = xsbase + (size_t)s * n * 64;
        w = wk + layer * 4096; b = bk + layer * 64;
        dst = K + (size_t)s * n * 64;
        relu_in = (s >= 1);
    } else {
        int s = job - t - 1;
        src = xsbase + (size_t)s * n * 64;
        w = wv + layer * 4096; b = bv + layer * 64;
        dst = V + (size_t)s * n * 64;
        relu_in = (s >= 1);
    }
    __shared__ float xl[4][64];
    int oc = threadIdx.x & 63;
    int sub = threadIdx.x >> 6;
    int node0 = blockIdx.x * 4;
    {
        int node = node0 + sub;
        float v = (node < n) ? src[(size_t)node * 64 + oc] : 0.f;
        if (relu_in) v = fmaxf(v, 0.f);
        xl[sub][oc] = v;
    }
    __syncthreads();
    int node = node0 + sub;
    if (node >= n) return;
    float acc = 0.f;
#pragma unroll
    for (int c = 0; c < 64; ++c) acc += xl[sub][c] * w[c * 64 + oc];
    dst[(size_t)node * 64 + oc] = acc + b[oc];
}

// ---------------------------------------------------------------------------
// edge attention + scatter.  One wave (64 lanes) per edge; lane = channel.
// head = lane/8; per-head dot via shfl_xor within the 8-lane group.
// Edge ids >= E are self-loops (r = c = e - E).
// ---------------------------------------------------------------------------
__global__ __launch_bounds__(256) void k_edge(
    const int* __restrict__ ei, int E, int n, int t,
    const float* __restrict__ q, const float* __restrict__ K,
    const float* __restrict__ V, const float* __restrict__ dinv,
    float* __restrict__ outp) {
    int wid  = (int)((blockIdx.x * (size_t)blockDim.x + threadIdx.x) >> 6);
    int lane = threadIdx.x & 63;
    int Et = E + n;
    if (wid >= Et) return;
    int r, c;
    if (wid < E) { r = ei[wid]; c = ei[E + wid]; }
    else         { r = c = wid - E; }
    float norm = dinv[r] * dinv[c];
    float qv = q[(size_t)c * 64 + lane];
    const float inv_sqrt_d = 0.35355339059327373f;  // 1/sqrt(8)
    float sc[NUM_LAYERS];
    float m = -1e30f;
    for (int s = 0; s < t; ++s) {
        float kv = K[((size_t)s * n + r) * 64 + lane];
        float p = qv * kv;
        p += __shfl_xor(p, 1);
        p += __shfl_xor(p, 2);
        p += __shfl_xor(p, 4);
        p *= inv_sqrt_d;
        sc[s] = p;
        m = fmaxf(m, p);
    }
    float denom = 0.f;
    for (int s = 0; s < t; ++s) { sc[s] = __expf(sc[s] - m); denom += sc[s]; }
    float scale = norm / denom;
    float msg = 0.f;
    for (int s = 0; s < t; ++s) {
        float vv = V[((size_t)s * n + r) * 64 + lane];
        msg += sc[s] * vv;
    }
    atomicAdd(&outp[(size_t)c * 64 + lane], msg * scale);
}

// ---------------------------------------------------------------------------
// final: logits = relu(x3) @ W2 + b2, then log_softmax over 64 classes.
// One wave per node; lane = class. x-row shared via shfl.
// ---------------------------------------------------------------------------
__global__ __launch_bounds__(256) void k_final(
    const float* __restrict__ x3, const float* __restrict__ w,
    const float* __restrict__ b, float* __restrict__ outp, int n) {
    int wid  = (int)((blockIdx.x * (size_t)blockDim.x + threadIdx.x) >> 6);
    int lane = threadIdx.x & 63;
    if (wid >= n) return;
    float xv = fmaxf(x3[(size_t)wid * 64 + lane], 0.f);
    float acc = b[lane];
#pragma unroll
    for (int c = 0; c < 64; ++c) {
        float xc = __shfl(xv, c);
        acc += xc * w[c * 64 + lane];
    }
    float m = acc;
    for (int off = 1; off < 64; off <<= 1) m = fmaxf(m, __shfl_xor(m, off));
    float e = __expf(acc - m);
    float ssum = e;
    for (int off = 1; off < 64; off <<= 1) ssum += __shfl_xor(ssum, off);
    outp[(size_t)wid * 64 + lane] = acc - m - __logf(ssum);
}

// ---------------------------------------------------------------------------
extern "C" void kernel_launch(void* const* d_in, const int* in_sizes, int n_in,
                              void* d_out, int out_size, void* d_ws, size_t ws_size,
                              hipStream_t stream) {
    const float* x  = (const float*)d_in[0];
    const int*   ei = (const int*)d_in[1];
    const float* w1 = (const float*)d_in[2];
    const float* b1 = (const float*)d_in[3];
    const float* wq = (const float*)d_in[4];
    const float* bq = (const float*)d_in[5];
    const float* wk = (const float*)d_in[6];
    const float* bk = (const float*)d_in[7];
    const float* wv = (const float*)d_in[8];
    const float* bv = (const float*)d_in[9];
    const float* w2 = (const float*)d_in[10];
    const float* b2 = (const float*)d_in[11];
    float* outp = (float*)d_out;

    int n = in_sizes[0] / 256;
    int E = in_sizes[1] / 2;
    int Et = E + n;

    float* ws = (float*)d_ws;
    size_t off = 0;
    float* dinv = ws + off; off += (size_t)n;
    float* q    = ws + off; off += (size_t)n * 64;
    float* K    = ws + off; off += (size_t)n * 64 * NUM_LAYERS;
    float* V    = ws + off; off += (size_t)n * 64 * NUM_LAYERS;
    float* xs   = ws + off; off += (size_t)n * 64 * (NUM_LAYERS + 1);

    k_init_deg<<<(n + 255) / 256, 256, 0, stream>>>(dinv, n);
    k_count_deg<<<(E + 255) / 256, 256, 0, stream>>>(ei + E, dinv, E);
    k_dinv<<<(n + 255) / 256, 256, 0, stream>>>(dinv, n);

    k_lin1<<<(n + 3) / 4, 256, 0, stream>>>(x, w1, b1, xs, n);

    for (int l = 0; l < NUM_LAYERS; ++l) {
        int t = l + 1;
        dim3 grid((n + 3) / 4, 1 + 2 * t);
        k_qkv<<<grid, 256, 0, stream>>>(xs, wq, bq, wk, bk, wv, bv,
                                        q, K, V, n, l, t);
        float* dst = xs + (size_t)(l + 1) * n * 64;
        hipMemsetAsync(dst, 0, (size_t)n * 64 * sizeof(float), stream);
        long long threads = (long long)Et * 64;
        k_edge<<<(int)((threads + 255) / 256), 256, 0, stream>>>(
            ei, E, n, t, q, K, V, dinv, dst);
    }

    k_final<<<((int)(((long long)n * 64 + 255) / 256)), 256, 0, stream>>>(
        xs + (size_t)NUM_LAYERS * n * 64, w2, b2, outp, n);
}